// Round 7
// baseline (115.529 us; speedup 1.0000x reference)
//
#include <hip/hip_runtime.h>

// AAF loss, round 7: dot2 algebra + Self-table corrections (5 dynamic LDS reads
// per neighbor instead of 8), logit-space ln p (19 fewer logf/pixel), 5x5x19
// source-patch staging (475 global loads/block vs 24.6K), LBsum precomputed.
// LDS ~51 KB -> 3 blocks/CU. fp16 (a, dd=ln a - ln b, lb=ln b) class-pair layout,
// pair-row stride 11 words (odd -> conflict-free for static class loops).

#define NC 19
#define HH 512
#define WW 512
#define NB 2
#define TS 16
#define HS 18                          // TS + 2 halo
#define HP (HS * HS)                   // 324
#define NPAIR 10                       // ceil(19/2)
#define RS 11                          // pair-row stride (words)
#define PS 25                          // 5x5 patch per class
#define NBLK (NB * (HH / TS) * (WW / TS))   // 2048
#define LOGEPS -9.210340371976182f     // log(1e-4)

typedef _Float16 f16x2 __attribute__((ext_vector_type(2)));

#if __has_builtin(__builtin_amdgcn_fdot2)
#define FDOT2(a, b, c) __builtin_amdgcn_fdot2((a), (b), (c), false)
#else
#define FDOT2(a, b, c) fmaf((float)(a)[1], (float)(b)[1], fmaf((float)(a)[0], (float)(b)[0], (c)))
#endif

struct Part { float es, ns; int ec, nc; };

__device__ __forceinline__ float extf(f16x2 v, int h) {
    return h ? (float)v[1] : (float)v[0];
}

__global__ __launch_bounds__(256, 3) void k_fused(const float* __restrict__ preds,
                                                  const int* __restrict__ targets,
                                                  const float* __restrict__ w_edge,
                                                  const float* __restrict__ w_not_edge,
                                                  Part* __restrict__ pb) {
    __shared__ f16x2 A2[HP * RS];    // a  (class pairs), pad class a=0
    __shared__ f16x2 D2[HP * RS];    // dd = ln a - ln b
    __shared__ f16x2 L2[HP * RS];    // lb = ln b
    __shared__ float U[HP];          // sum_c (a*dd + lb)   (fp16-consistent)
    __shared__ float LBS[HP];        // sum_c lb
    __shared__ int   TG[HP];         // labels incl. halo (255 for image-OOB)
    __shared__ float4 SelfBuf[HP];   // stage>=1.5: (a,dd,lb)@own-label; stage 1: patch alias
    __shared__ float swe[NC], swn[NC];

    float* patch = (float*)SelfBuf;  // 19*25 floats = 1.9 KB <= 5.2 KB

    const int tid = threadIdx.x;
    const int bx = blockIdx.x, by = blockIdx.y, n = blockIdx.z;

    if (tid < NC) {
        {
            float a = w_edge[tid * 3 + 0], b = w_edge[tid * 3 + 1], c = w_edge[tid * 3 + 2];
            float m = fmaxf(a, fmaxf(b, c));
            float ea = __expf(a - m), eb = __expf(b - m), ec = __expf(c - m);
            swe[tid] = ea / (ea + eb + ec);
        }
        {
            float a = w_not_edge[tid * 3 + 0], b = w_not_edge[tid * 3 + 1], c = w_not_edge[tid * 3 + 2];
            float m = fmaxf(a, fmaxf(b, c));
            float ea = __expf(a - m), eb = __expf(b - m), ec = __expf(c - m);
            swn[tid] = ea / (ea + eb + ec);
        }
    }

    const int* tg = targets + (n << 18);
    const float* pbase = preds + (size_t)n * NC * 4096;

    // ---- stage 0: stage source patch (5 rows x 5 cols x 19 classes) ----
    const int yT = max(by * TS - 1, 0), xL = max(bx * TS - 1, 0);
    const int y0b = (yT * 63) / 511, x0b = (xL * 63) / 511;
    for (int t = tid; t < NC * PS; t += 256) {
        const int c = t / PS, r = t - c * PS;
        const int ry = r / 5, rx = r - ry * 5;
        const int sy = min(y0b + ry, 63), sx = min(x0b + rx, 63);
        patch[t] = pbase[c * 4096 + (sy << 6) + sx];
    }
    __syncthreads();

    // ---- stage 1: halo softmax -> packed (a, dd, lb) + U + LBS ----
    for (int i = tid; i < HP; i += 256) {
        const int hy = i / HS, hx = i - hy * HS;
        const int y = by * TS + hy - 1;
        const int x = bx * TS + hx - 1;
        if (((unsigned)y >= (unsigned)HH) | ((unsigned)x >= (unsigned)WW)) {
            TG[i] = 255;
            const _Float16 aP = (_Float16)1e-4f, dP = (_Float16)LOGEPS, lP = (_Float16)0.0f;
#pragma unroll
            for (int j = 0; j < NPAIR - 1; ++j) {
                A2[i * RS + j] = (f16x2){aP, aP};
                D2[i * RS + j] = (f16x2){dP, dP};
                L2[i * RS + j] = (f16x2){lP, lP};
            }
            A2[i * RS + 9] = (f16x2){aP, (_Float16)0.0f};
            D2[i * RS + 9] = (f16x2){dP, (_Float16)0.0f};
            L2[i * RS + 9] = (f16x2){lP, lP};
            U[i] = 19.0f * ((float)aP * (float)dP);
            LBS[i] = 0.0f;
        } else {
            TG[i] = tg[(y << 9) + x];
            const float fy = (float)(y * 63) / 511.0f;
            const float fx = (float)(x * 63) / 511.0f;
            const int y0 = (int)fy, x0 = (int)fx;
            const float wy = fy - (float)y0, wx = fx - (float)x0;
            const int y1 = min(y0 + 1, 63), x1 = min(x0 + 1, 63);
            const float omwy = 1.0f - wy, omwx = 1.0f - wx;
            const int o00 = (y0 - y0b) * 5 + (x0 - x0b);
            const int o01 = (y0 - y0b) * 5 + (x1 - x0b);
            const int o10 = (y1 - y0b) * 5 + (x0 - x0b);
            const int o11 = (y1 - y0b) * 5 + (x1 - x0b);

            float v[NC], w[NC];
            float m = -1e30f;
#pragma unroll
            for (int c = 0; c < NC; ++c) {
                const float* pc_ = &patch[c * PS];
                const float a = pc_[o00] * omwy + pc_[o10] * wy;
                const float b = pc_[o01] * omwy + pc_[o11] * wy;
                const float vv = a * omwx + b * wx;
                v[c] = vv;
                m = fmaxf(m, vv);
            }
            float s = 0.0f;
#pragma unroll
            for (int c = 0; c < NC; ++c) { w[c] = __expf(v[c] - m); s += w[c]; }
            const float inv = 1.0f / s;
            const float lns = __logf(s) + m;     // v - lns = ln p
            float u = 0.0f, lbs = 0.0f;
            _Float16 pa = (_Float16)0.0f, pd = (_Float16)0.0f, pl = (_Float16)0.0f;
#pragma unroll
            for (int c = 0; c < NC; ++c) {
                const float p = w[c] * inv;
                const float la = fmaxf(v[c] - lns, LOGEPS);      // ln(clip p)
                const float aC = fmaxf(p, 1e-4f);
                const float lb = __logf(fmaxf(1.0f - p, 1e-4f));
                const float dd = la - lb;
                const _Float16 a16 = (_Float16)aC, d16 = (_Float16)dd, l16 = (_Float16)lb;
                u = fmaf((float)a16, (float)d16, u + (float)l16);
                lbs += (float)l16;
                if (c & 1) {
                    const int j = c >> 1;
                    A2[i * RS + j] = (f16x2){pa, a16};
                    D2[i * RS + j] = (f16x2){pd, d16};
                    L2[i * RS + j] = (f16x2){pl, l16};
                } else { pa = a16; pd = d16; pl = l16; }
            }
            A2[i * RS + 9] = (f16x2){pa, (_Float16)0.0f};   // class 18 + zero pad
            D2[i * RS + 9] = (f16x2){pd, (_Float16)0.0f};
            L2[i * RS + 9] = (f16x2){pl, (_Float16)0.0f};
            U[i] = u;
            LBS[i] = lbs;
        }
    }
    __syncthreads();

    // ---- stage 1.5: Self table (a, dd, lb at own label) -- overwrites patch ----
    for (int i = tid; i < HP; i += 256) {
        const int lab = TG[i];
        float4 sf = make_float4(0.0f, 0.0f, 0.0f, 0.0f);
        if (lab <= NC - 1) {
            const int pl = lab >> 1, hl = lab & 1;
            sf.x = extf(A2[i * RS + pl], hl);
            sf.y = extf(D2[i * RS + pl], hl);
            sf.z = extf(L2[i * RS + pl], hl);
        }
        SelfBuf[i] = sf;
    }
    __syncthreads();

    // ---- stage 2 ----
    const int ty = tid >> 4, tx = tid & 15;
    const int hi = (ty + 1) * HS + (tx + 1);
    const int lab = TG[hi];
    const bool interior_blk = (bx > 0) & (bx < 31) & (by > 0) & (by < 31);

    float e_s = 0.0f, ne_s = 0.0f;
    int e_c = 0, ne_c = 0;
    const int DOFF[8] = {-HS - 1, -HS, -HS + 1, -1, 1, HS - 1, HS, HS + 1};

    if (interior_blk) {
        f16x2 Dh[NPAIR];
#pragma unroll
        for (int j = 0; j < NPAIR; ++j) Dh[j] = D2[hi * RS + j];
        const float4 Sh = SelfBuf[hi];          // (a,dd,lb) @ lab (center)
        const float ddhL = Sh.y, lbhL = Sh.z;
        const float Lsum = LBS[hi];
        const int plab = lab >> 1, hlab = lab & 1;

#pragma unroll
        for (int k = 0; k < 8; ++k) {
            const int np = hi + DOFF[k];
            const int nlab = TG[np];
            const int nb_ = np * RS;
            float dot = 0.0f;
#pragma unroll
            for (int j = 0; j < NPAIR; ++j) dot = FDOT2(A2[nb_ + j], Dh[j], dot);
            const float klsum = U[np] - dot - Lsum;

            // kl1 @ c = lab: 3 dynamic reads (neighbor row)
            const float a1 = extf(A2[nb_ + plab], hlab);
            const float d1 = extf(D2[nb_ + plab], hlab);
            const float l1 = extf(L2[nb_ + plab], hlab);
            const float kl1 = fmaf(a1, d1 - ddhL, l1 - lbhL);

            // kl2 @ c = nlab: neighbor Self (static) + 2 dynamic reads (center row)
            const float4 Sn = SelfBuf[np];
            const int pn = nlab >> 1, hn = nlab & 1;
            const float dh2 = extf(D2[hi * RS + pn], hn);
            const float lh2 = extf(L2[hi * RS + pn], hn);
            const float kl2 = fmaf(Sn.x, Sn.y - dh2, Sn.z - lh2);

            const bool df = (lab != nlab);
            const float w = df ? 1.0f : 0.0f;
            e_s = fmaf(w, fmaxf(3.0f - kl1, 0.0f) + fmaxf(3.0f - kl2, 0.0f), e_s);
            ne_s += klsum - w * (kl1 + kl2);
            e_c += df ? 2 : 0;
        }
        ne_c = 8 * NC - e_c;
        e_s *= swe[lab];
        ne_s *= swn[lab];
    } else if (lab <= NC - 1) {
        // border: general masked per-class path
        f16x2 Dh2[NPAIR], Lh2[NPAIR];
#pragma unroll
        for (int j = 0; j < NPAIR; ++j) { Dh2[j] = D2[hi * RS + j]; Lh2[j] = L2[hi * RS + j]; }
        const unsigned mlab = 1u << lab;
#pragma unroll
        for (int k = 0; k < 8; ++k) {
            const int off = DOFF[k];
            const int rlab = TG[hi - off];
            const int np = hi + off;
            const int nlab = TG[np];
            const unsigned mask = (nlab <= NC - 1) ? (mlab ^ (1u << nlab))
                                : ((nlab == 255) ? 0x7FFFFu : mlab);
            const int nb_ = np * RS;
            float ek = 0.0f, nk = 0.0f;
#pragma unroll
            for (int j = 0; j < NPAIR; ++j) {
                const f16x2 an = A2[nb_ + j];
                const f16x2 dn = D2[nb_ + j];
                const f16x2 ln_ = L2[nb_ + j];
#pragma unroll
                for (int h = 0; h < 2; ++h) {
                    const int c = 2 * j + h;
                    if (c >= NC) break;
                    const float kl = fmaf((float)an[h], (float)dn[h] - (float)Dh2[j][h],
                                          (float)ln_[h] - (float)Lh2[j][h]);
                    const float ef = (float)((mask >> c) & 1u);
                    ek = fmaf(ef, fmaxf(3.0f - kl, 0.0f), ek);
                    nk = fmaf(1.0f - ef, kl, nk);
                }
            }
            const bool valid = (rlab <= NC - 1);
            const float vf = valid ? 1.0f : 0.0f;
            e_s = fmaf(vf, ek, e_s);
            ne_s = fmaf(vf, nk, ne_s);
            const int pc = __popc(mask);
            e_c += valid ? pc : 0;
            ne_c += valid ? (NC - pc) : 0;
        }
        e_s *= swe[lab];
        ne_s *= swn[lab];
    }

    // ---- block reduction ----
#pragma unroll
    for (int off = 32; off > 0; off >>= 1) {
        e_s  += __shfl_down(e_s, off, 64);
        ne_s += __shfl_down(ne_s, off, 64);
        e_c  += __shfl_down(e_c, off, 64);
        ne_c += __shfl_down(ne_c, off, 64);
    }
    __shared__ float r_es[4], r_ns[4];
    __shared__ int r_ec[4], r_nc[4];
    const int wid = tid >> 6, lane = tid & 63;
    if (lane == 0) { r_es[wid] = e_s; r_ns[wid] = ne_s; r_ec[wid] = e_c; r_nc[wid] = ne_c; }
    __syncthreads();
    if (tid == 0) {
        float tes = 0.0f, tns = 0.0f;
        int tec = 0, tnc = 0;
#pragma unroll
        for (int w = 0; w < 4; ++w) { tes += r_es[w]; tns += r_ns[w]; tec += r_ec[w]; tnc += r_nc[w]; }
        const int bid = (blockIdx.z * gridDim.y + blockIdx.y) * gridDim.x + blockIdx.x;
        pb[bid].es = tes; pb[bid].ns = tns; pb[bid].ec = tec; pb[bid].nc = tnc;
    }
}

// ---------------- final reduce (1 block) ----------------
__global__ __launch_bounds__(256) void k_final(const Part* __restrict__ pb,
                                               float* __restrict__ out) {
    const int tid = threadIdx.x;
    double es = 0.0, ns = 0.0;
    long long ec = 0, nc = 0;
    for (int i = tid; i < NBLK; i += 256) {
        es += (double)pb[i].es; ns += (double)pb[i].ns;
        ec += pb[i].ec; nc += pb[i].nc;
    }
#pragma unroll
    for (int off = 32; off > 0; off >>= 1) {
        es += __shfl_down(es, off, 64);
        ns += __shfl_down(ns, off, 64);
        ec += __shfl_down(ec, off, 64);
        nc += __shfl_down(nc, off, 64);
    }
    __shared__ double ses[4], sns[4];
    __shared__ long long sec[4], snc[4];
    const int wid = tid >> 6, lane = tid & 63;
    if (lane == 0) { ses[wid] = es; sns[wid] = ns; sec[wid] = ec; snc[wid] = nc; }
    __syncthreads();
    if (tid == 0) {
        double tes = 0.0, tns = 0.0;
        long long tec = 0, tnc = 0;
#pragma unroll
        for (int w = 0; w < 4; ++w) { tes += ses[w]; tns += sns[w]; tec += sec[w]; tnc += snc[w]; }
        double ecd = (double)tec; if (ecd < 1.0) ecd = 1.0;
        double ncd = (double)tnc; if (ncd < 1.0) ncd = 1.0;
        out[0] = (float)((tes / ecd) * 0.01 + (tns / ncd) * 0.01);
    }
}

extern "C" void kernel_launch(void* const* d_in, const int* in_sizes, int n_in,
                              void* d_out, int out_size, void* d_ws, size_t ws_size,
                              hipStream_t stream) {
    const float* preds      = (const float*)d_in[0];  // (2,19,64,64) fp32
    const int*   targets    = (const int*)d_in[1];    // (2,512,512) int32
    const float* w_edge     = (const float*)d_in[2];  // (1,1,1,19,1,3) fp32
    const float* w_not_edge = (const float*)d_in[3];

    Part* pb = (Part*)d_ws;

    dim3 grid(WW / TS, HH / TS, NB);
    k_fused<<<grid, 256, 0, stream>>>(preds, targets, w_edge, w_not_edge, pb);
    k_final<<<1, 256, 0, stream>>>(pb, (float*)d_out);
}

// Round 8
// 112.803 us; speedup vs baseline: 1.0242x; 1.0242x over previous
//
#include <hip/hip_runtime.h>

// AAF loss, round 8: occupancy push. Drop the L (ln b) LDS array — recompute
// l = ln(1-a) via __logf only at the <=2 correction classes per neighbor.
// LDS ~38 KB -> 4 blocks/CU (was 3), grid = exactly 2 rounds of 1024 blocks.
// Self table per halo pixel: (a, d, l, t=a*d+l) @ own label, float4 static read.
// Corrections per neighbor: 4 dynamic b32 + 2 logf. Bulk term unchanged:
// sum_c kl = U[np] - dot2(a_n, d_h) - LBS[hi].

#define NC 19
#define HH 512
#define WW 512
#define NB 2
#define TS 16
#define HS 18                          // TS + 2 halo
#define HP (HS * HS)                   // 324
#define NPAIR 10                       // ceil(19/2)
#define RS 11                          // pair-row stride (words), odd -> conflict-free
#define PS 25                          // 5x5 patch per class
#define NBLK (NB * (HH / TS) * (WW / TS))   // 2048
#define LOGEPS -9.210340371976182f     // log(1e-4)

typedef _Float16 f16x2 __attribute__((ext_vector_type(2)));

#if __has_builtin(__builtin_amdgcn_fdot2)
#define FDOT2(a, b, c) __builtin_amdgcn_fdot2((a), (b), (c), false)
#else
#define FDOT2(a, b, c) fmaf((float)(a)[1], (float)(b)[1], fmaf((float)(a)[0], (float)(b)[0], (c)))
#endif

struct Part { float es, ns; int ec, nc; };

__device__ __forceinline__ float extf(f16x2 v, int h) {
    return h ? (float)v[1] : (float)v[0];
}

__global__ __launch_bounds__(256, 4) void k_fused(const float* __restrict__ preds,
                                                  const int* __restrict__ targets,
                                                  const float* __restrict__ w_edge,
                                                  const float* __restrict__ w_not_edge,
                                                  Part* __restrict__ pb) {
    __shared__ f16x2 A2[HP * RS];    // a (class pairs), pad class a=0
    __shared__ f16x2 D2[HP * RS];    // d = ln a - ln b
    __shared__ float U[HP];          // sum_c (a*d + l)
    __shared__ float LBS[HP];        // sum_c l
    __shared__ int   TG[HP];         // labels incl. halo (255 for image-OOB)
    __shared__ float4 SelfBuf[HP];   // (a, d, l, t) @ own label; stage 0: patch alias
    __shared__ float swe[NC], swn[NC];

    float* patch = (float*)SelfBuf;  // 19*25 floats = 1.9 KB <= 5.2 KB

    const int tid = threadIdx.x;
    const int bx = blockIdx.x, by = blockIdx.y, n = blockIdx.z;

    if (tid < NC) {
        {
            float a = w_edge[tid * 3 + 0], b = w_edge[tid * 3 + 1], c = w_edge[tid * 3 + 2];
            float m = fmaxf(a, fmaxf(b, c));
            float ea = __expf(a - m), eb = __expf(b - m), ec = __expf(c - m);
            swe[tid] = ea / (ea + eb + ec);
        }
        {
            float a = w_not_edge[tid * 3 + 0], b = w_not_edge[tid * 3 + 1], c = w_not_edge[tid * 3 + 2];
            float m = fmaxf(a, fmaxf(b, c));
            float ea = __expf(a - m), eb = __expf(b - m), ec = __expf(c - m);
            swn[tid] = ea / (ea + eb + ec);
        }
    }

    const int* tg = targets + (n << 18);
    const float* pbase = preds + (size_t)n * NC * 4096;

    // ---- stage 0: stage 5x5x19 source patch ----
    const int yT = max(by * TS - 1, 0), xL = max(bx * TS - 1, 0);
    const int y0b = (yT * 63) / 511, x0b = (xL * 63) / 511;
    for (int t = tid; t < NC * PS; t += 256) {
        const int c = t / PS, r = t - c * PS;
        const int ry = r / 5, rx = r - ry * 5;
        const int sy = min(y0b + ry, 63), sx = min(x0b + rx, 63);
        patch[t] = pbase[c * 4096 + (sy << 6) + sx];
    }
    __syncthreads();

    // ---- stage 1: halo softmax -> packed (a, d) + U + LBS ----
    for (int i = tid; i < HP; i += 256) {
        const int hy = i / HS, hx = i - hy * HS;
        const int y = by * TS + hy - 1;
        const int x = bx * TS + hx - 1;
        if (((unsigned)y >= (unsigned)HH) | ((unsigned)x >= (unsigned)WW)) {
            TG[i] = 255;
            const _Float16 aP = (_Float16)1e-4f, dP = (_Float16)LOGEPS;
#pragma unroll
            for (int j = 0; j < NPAIR - 1; ++j) {
                A2[i * RS + j] = (f16x2){aP, aP};
                D2[i * RS + j] = (f16x2){dP, dP};
            }
            A2[i * RS + 9] = (f16x2){aP, (_Float16)0.0f};
            D2[i * RS + 9] = (f16x2){dP, (_Float16)0.0f};
            U[i] = 19.0f * (1e-4f * LOGEPS);   // l = ln 1 = 0
            LBS[i] = 0.0f;
        } else {
            TG[i] = tg[(y << 9) + x];
            const float fy = (float)(y * 63) / 511.0f;
            const float fx = (float)(x * 63) / 511.0f;
            const int y0 = (int)fy, x0 = (int)fx;
            const float wy = fy - (float)y0, wx = fx - (float)x0;
            const int y1 = min(y0 + 1, 63), x1 = min(x0 + 1, 63);
            const float omwy = 1.0f - wy, omwx = 1.0f - wx;
            const int o00 = (y0 - y0b) * 5 + (x0 - x0b);
            const int o01 = (y0 - y0b) * 5 + (x1 - x0b);
            const int o10 = (y1 - y0b) * 5 + (x0 - x0b);
            const int o11 = (y1 - y0b) * 5 + (x1 - x0b);

            float v[NC], w[NC];
            float m = -1e30f;
#pragma unroll
            for (int c = 0; c < NC; ++c) {
                const float* pc_ = &patch[c * PS];
                const float a = pc_[o00] * omwy + pc_[o10] * wy;
                const float b = pc_[o01] * omwy + pc_[o11] * wy;
                const float vv = a * omwx + b * wx;
                v[c] = vv;
                m = fmaxf(m, vv);
            }
            float s = 0.0f;
#pragma unroll
            for (int c = 0; c < NC; ++c) { w[c] = __expf(v[c] - m); s += w[c]; }
            const float inv = 1.0f / s;
            const float lns = __logf(s) + m;     // v - lns = ln p
            float u = 0.0f, lbs = 0.0f;
            _Float16 pa = (_Float16)0.0f, pd = (_Float16)0.0f;
#pragma unroll
            for (int c = 0; c < NC; ++c) {
                const float p = w[c] * inv;
                const float la = fmaxf(v[c] - lns, LOGEPS);      // ln(clip p)
                const float aC = fmaxf(p, 1e-4f);
                const float lb = __logf(fmaxf(1.0f - p, 1e-4f));
                const float dd = la - lb;
                const _Float16 a16 = (_Float16)aC, d16 = (_Float16)dd;
                u = fmaf((float)a16, (float)d16, u + lb);
                lbs += lb;
                if (c & 1) {
                    const int j = c >> 1;
                    A2[i * RS + j] = (f16x2){pa, a16};
                    D2[i * RS + j] = (f16x2){pd, d16};
                } else { pa = a16; pd = d16; }
            }
            A2[i * RS + 9] = (f16x2){pa, (_Float16)0.0f};   // class 18 + zero pad
            D2[i * RS + 9] = (f16x2){pd, (_Float16)0.0f};
            U[i] = u;
            LBS[i] = lbs;
        }
    }
    __syncthreads();

    // ---- stage 1.5: Self table (a, d, l, t) @ own label ----
    for (int i = tid; i < HP; i += 256) {
        const int lab = TG[i];
        float4 sf;
        if (lab <= NC - 1) {
            const int pl = lab >> 1, hl = lab & 1;
            const float a = extf(A2[i * RS + pl], hl);
            const float d = extf(D2[i * RS + pl], hl);
            const float l = __logf(fmaxf(1.0f - a, 1e-4f));
            sf = make_float4(a, d, l, fmaf(a, d, l));
        } else {
            sf = make_float4(1e-4f, LOGEPS, 0.0f, 1e-4f * LOGEPS);
        }
        SelfBuf[i] = sf;
    }
    __syncthreads();

    // ---- stage 2 ----
    const int ty = tid >> 4, tx = tid & 15;
    const int hi = (ty + 1) * HS + (tx + 1);
    const int lab = TG[hi];
    const bool interior_blk = (bx > 0) & (bx < 31) & (by > 0) & (by < 31);

    float e_s = 0.0f, ne_s = 0.0f;
    int e_c = 0, ne_c = 0;
    const int DOFF[8] = {-HS - 1, -HS, -HS + 1, -1, 1, HS - 1, HS, HS + 1};

    if (interior_blk) {
        f16x2 Dh[NPAIR];
#pragma unroll
        for (int j = 0; j < NPAIR; ++j) Dh[j] = D2[hi * RS + j];
        const float4 Sh = SelfBuf[hi];           // (a,d,l,t) @ lab, center
        const float Lsum = LBS[hi];
        const int plab = lab >> 1, hlab = lab & 1;

#pragma unroll
        for (int k = 0; k < 8; ++k) {
            const int np = hi + DOFF[k];
            const int nlab = TG[np];
            const int nb_ = np * RS;
            float dot = 0.0f;
#pragma unroll
            for (int j = 0; j < NPAIR; ++j) dot = FDOT2(A2[nb_ + j], Dh[j], dot);
            const float klsum = U[np] - dot - Lsum;

            // kl1 @ c = lab: neighbor (a,d) dyn + logf; center from Self
            const float a1 = extf(A2[nb_ + plab], hlab);
            const float d1 = extf(D2[nb_ + plab], hlab);
            const float l1 = __logf(fmaxf(1.0f - a1, 1e-4f));
            const float kl1 = fmaf(a1, d1 - Sh.y, l1 - Sh.z);

            // kl2 @ c = nlab: neighbor Self (static b128) + center (a,d) dyn + logf
            const float4 Sn = SelfBuf[np];
            const int pn = nlab >> 1, hn = nlab & 1;
            const float dh2 = extf(D2[hi * RS + pn], hn);
            const float ah2 = extf(A2[hi * RS + pn], hn);
            const float lh2 = __logf(fmaxf(1.0f - ah2, 1e-4f));
            const float kl2 = Sn.w - fmaf(Sn.x, dh2, lh2);

            const bool df = (lab != nlab);
            const float w = df ? 1.0f : 0.0f;
            e_s = fmaf(w, fmaxf(3.0f - kl1, 0.0f) + fmaxf(3.0f - kl2, 0.0f), e_s);
            ne_s += klsum - w * (kl1 + kl2);
            e_c += df ? 2 : 0;
        }
        ne_c = 8 * NC - e_c;
        e_s *= swe[lab];
        ne_s *= swn[lab];
    } else if (lab <= NC - 1) {
        // ---- border path: exact semantics incl. OOB pad / ignore labels ----
        f16x2 Dh[NPAIR], Ah[NPAIR];
#pragma unroll
        for (int j = 0; j < NPAIR; ++j) { Dh[j] = D2[hi * RS + j]; Ah[j] = A2[hi * RS + j]; }
        const float4 Sh = SelfBuf[hi];
        const float Lsum = LBS[hi];
        const int plab = lab >> 1, hlab = lab & 1;

#pragma unroll
        for (int k = 0; k < 8; ++k) {
            const int off = DOFF[k];
            const int rlab = TG[hi - off];       // reversed-offset ignore source
            const int np = hi + off;
            const int nlab = TG[np];
            const int nb_ = np * RS;
            float dot = 0.0f;
#pragma unroll
            for (int j = 0; j < NPAIR; ++j) dot = FDOT2(A2[nb_ + j], Dh[j], dot);
            const float klsum = U[np] - dot - Lsum;

            float ek, ne_k; int pc;
            if (nlab <= NC - 1) {
                const float a1 = extf(A2[nb_ + plab], hlab);
                const float d1 = extf(D2[nb_ + plab], hlab);
                const float l1 = __logf(fmaxf(1.0f - a1, 1e-4f));
                const float kl1 = fmaf(a1, d1 - Sh.y, l1 - Sh.z);
                const float4 Sn = SelfBuf[np];
                const int pn = nlab >> 1, hn = nlab & 1;
                const float dh2 = extf(D2[hi * RS + pn], hn);
                const float ah2 = extf(A2[hi * RS + pn], hn);
                const float lh2 = __logf(fmaxf(1.0f - ah2, 1e-4f));
                const float kl2 = Sn.w - fmaf(Sn.x, dh2, lh2);
                const bool df = (lab != nlab);
                const float w = df ? 1.0f : 0.0f;
                ek = w * (fmaxf(3.0f - kl1, 0.0f) + fmaxf(3.0f - kl2, 0.0f));
                ne_k = klsum - w * (kl1 + kl2);
                pc = df ? 2 : 0;
            } else if (nlab == 255) {
                // pad neighbor: all 19 classes edge; kl_c = 1e-4*(LOGEPS - la_h) - lb_h
                ek = 0.0f;
#pragma unroll
                for (int j = 0; j < NPAIR; ++j) {
#pragma unroll
                    for (int h = 0; h < 2; ++h) {
                        const int c = 2 * j + h;
                        if (c >= NC) break;
                        const float ah = extf(Ah[j], h);
                        const float dh = extf(Dh[j], h);
                        const float lh = __logf(fmaxf(1.0f - ah, 1e-4f));
                        const float kl = 1e-4f * (LOGEPS - (dh + lh)) - lh;
                        ek += fmaxf(3.0f - kl, 0.0f);
                    }
                }
                ne_k = 0.0f;
                pc = NC;
            } else {
                // ignore-class neighbor (19..254): edge only at c = lab
                const float a1 = extf(A2[nb_ + plab], hlab);
                const float d1 = extf(D2[nb_ + plab], hlab);
                const float l1 = __logf(fmaxf(1.0f - a1, 1e-4f));
                const float kl1 = fmaf(a1, d1 - Sh.y, l1 - Sh.z);
                ek = fmaxf(3.0f - kl1, 0.0f);
                ne_k = klsum - kl1;
                pc = 1;
            }
            const bool valid = (rlab <= NC - 1);
            const float vf = valid ? 1.0f : 0.0f;
            e_s = fmaf(vf, ek, e_s);
            ne_s = fmaf(vf, ne_k, ne_s);
            e_c += valid ? pc : 0;
            ne_c += valid ? (NC - pc) : 0;
        }
        e_s *= swe[lab];
        ne_s *= swn[lab];
    }

    // ---- block reduction ----
#pragma unroll
    for (int off = 32; off > 0; off >>= 1) {
        e_s  += __shfl_down(e_s, off, 64);
        ne_s += __shfl_down(ne_s, off, 64);
        e_c  += __shfl_down(e_c, off, 64);
        ne_c += __shfl_down(ne_c, off, 64);
    }
    __shared__ float r_es[4], r_ns[4];
    __shared__ int r_ec[4], r_nc[4];
    const int wid = tid >> 6, lane = tid & 63;
    if (lane == 0) { r_es[wid] = e_s; r_ns[wid] = ne_s; r_ec[wid] = e_c; r_nc[wid] = ne_c; }
    __syncthreads();
    if (tid == 0) {
        float tes = 0.0f, tns = 0.0f;
        int tec = 0, tnc = 0;
#pragma unroll
        for (int w = 0; w < 4; ++w) { tes += r_es[w]; tns += r_ns[w]; tec += r_ec[w]; tnc += r_nc[w]; }
        const int bid = (blockIdx.z * gridDim.y + blockIdx.y) * gridDim.x + blockIdx.x;
        pb[bid].es = tes; pb[bid].ns = tns; pb[bid].ec = tec; pb[bid].nc = tnc;
    }
}

// ---------------- final reduce (1 block) ----------------
__global__ __launch_bounds__(256) void k_final(const Part* __restrict__ pb,
                                               float* __restrict__ out) {
    const int tid = threadIdx.x;
    double es = 0.0, ns = 0.0;
    long long ec = 0, nc = 0;
    for (int i = tid; i < NBLK; i += 256) {
        es += (double)pb[i].es; ns += (double)pb[i].ns;
        ec += pb[i].ec; nc += pb[i].nc;
    }
#pragma unroll
    for (int off = 32; off > 0; off >>= 1) {
        es += __shfl_down(es, off, 64);
        ns += __shfl_down(ns, off, 64);
        ec += __shfl_down(ec, off, 64);
        nc += __shfl_down(nc, off, 64);
    }
    __shared__ double ses[4], sns[4];
    __shared__ long long sec[4], snc[4];
    const int wid = tid >> 6, lane = tid & 63;
    if (lane == 0) { ses[wid] = es; sns[wid] = ns; sec[wid] = ec; snc[wid] = nc; }
    __syncthreads();
    if (tid == 0) {
        double tes = 0.0, tns = 0.0;
        long long tec = 0, tnc = 0;
#pragma unroll
        for (int w = 0; w < 4; ++w) { tes += ses[w]; tns += sns[w]; tec += sec[w]; tnc += snc[w]; }
        double ecd = (double)tec; if (ecd < 1.0) ecd = 1.0;
        double ncd = (double)tnc; if (ncd < 1.0) ncd = 1.0;
        out[0] = (float)((tes / ecd) * 0.01 + (tns / ncd) * 0.01);
    }
}

extern "C" void kernel_launch(void* const* d_in, const int* in_sizes, int n_in,
                              void* d_out, int out_size, void* d_ws, size_t ws_size,
                              hipStream_t stream) {
    const float* preds      = (const float*)d_in[0];  // (2,19,64,64) fp32
    const int*   targets    = (const int*)d_in[1];    // (2,512,512) int32
    const float* w_edge     = (const float*)d_in[2];  // (1,1,1,19,1,3) fp32
    const float* w_not_edge = (const float*)d_in[3];

    Part* pb = (Part*)d_ws;

    dim3 grid(WW / TS, HH / TS, NB);
    k_fused<<<grid, 256, 0, stream>>>(preds, targets, w_edge, w_not_edge, pb);
    k_final<<<1, 256, 0, stream>>>(pb, (float*)d_out);
}

// Round 9
// 104.041 us; speedup vs baseline: 1.1104x; 1.0842x over previous
//
#include <hip/hip_runtime.h>
#include <stdint.h>

// AAF loss, round 9: packed-fp16 fully-static stage 2 (R4 pipeline regime).
// LDS per halo pixel: ATpk = interleaved (a-pair, t-pair) f16x2 words, stride 22
// (b64 reads, 8B aligned, conflict-free); Dpk = d-pairs, stride 11 (odd).
// a = clip(p), d = ln a - ln b, l = ln b derived in prologue as l = t - a*d;
// t = RN(fma(a16, d16, l16)) for structural cancellation in kl = t_n - (a_n*d_h + l_h).
// Inner loop: 10x (ds_read_b64 + pk_fma + pk_sub + fdot2 + 2 select) per neighbor;
// kl@lab / kl@nlab captured via cndmask during the unrolled loop -> zero dynamic
// LDS reads, zero logf in stage 2. Class slot 19 padded to kl == 0.

#define NC 19
#define HH 512
#define WW 512
#define NB 2
#define TS 16
#define HS 18                          // TS + 2 halo
#define HP (HS * HS)                   // 324
#define NPAIR 10
#define ATRS 22                        // ATpk stride in words (even -> b64 aligned)
#define DRS 11                         // Dpk stride in words (odd -> conflict-free)
#define PS 25                          // 5x5 source patch per class
#define NBLK (NB * (HH / TS) * (WW / TS))   // 2048
#define LOGEPS -9.210340371976182f     // log(1e-4)

typedef _Float16 f16x2 __attribute__((ext_vector_type(2)));

#if __has_builtin(__builtin_amdgcn_fdot2)
#define FDOT2(a, b, c) __builtin_amdgcn_fdot2((a), (b), (c), false)
#else
#define FDOT2(a, b, c) fmaf((float)(a)[1], (float)(b)[1], fmaf((float)(a)[0], (float)(b)[0], (c)))
#endif

struct Part { float es, ns; int ec, nc; };

union U32F2 { uint32_t u; f16x2 h; };
__device__ __forceinline__ uint32_t bc_u32(f16x2 v) { U32F2 x; x.h = v; return x.u; }
__device__ __forceinline__ f16x2 bc_h2(uint32_t v) { U32F2 x; x.u = v; return x.h; }
__device__ __forceinline__ float extf(f16x2 v, int h) { return h ? (float)v[1] : (float)v[0]; }

__global__ __launch_bounds__(256, 3) void k_fused(const float* __restrict__ preds,
                                                  const int* __restrict__ targets,
                                                  const float* __restrict__ w_edge,
                                                  const float* __restrict__ w_not_edge,
                                                  Part* __restrict__ pb) {
    __shared__ __align__(16) uint32_t AT[HP * ATRS];  // (a2,t2) interleaved pairs
    __shared__ uint32_t DP[HP * DRS];                 // d2 pairs
    __shared__ int   TG[HP];
    __shared__ float swe[NC], swn[NC];
    __shared__ float patch[NC * PS];

    const int tid = threadIdx.x;
    const int bx = blockIdx.x, by = blockIdx.y, n = blockIdx.z;

    if (tid < NC) {
        {
            float a = w_edge[tid * 3 + 0], b = w_edge[tid * 3 + 1], c = w_edge[tid * 3 + 2];
            float m = fmaxf(a, fmaxf(b, c));
            float ea = __expf(a - m), eb = __expf(b - m), ec = __expf(c - m);
            swe[tid] = ea / (ea + eb + ec);
        }
        {
            float a = w_not_edge[tid * 3 + 0], b = w_not_edge[tid * 3 + 1], c = w_not_edge[tid * 3 + 2];
            float m = fmaxf(a, fmaxf(b, c));
            float ea = __expf(a - m), eb = __expf(b - m), ec = __expf(c - m);
            swn[tid] = ea / (ea + eb + ec);
        }
    }

    const int* tg = targets + (n << 18);
    const float* pbase = preds + (size_t)n * NC * 4096;

    // ---- stage 0: stage 5x5x19 source patch ----
    const int yT = max(by * TS - 1, 0), xL = max(bx * TS - 1, 0);
    const int y0b = (yT * 63) / 511, x0b = (xL * 63) / 511;
    for (int t = tid; t < NC * PS; t += 256) {
        const int c = t / PS, r = t - c * PS;
        const int ry = r / 5, rx = r - ry * 5;
        const int sy = min(y0b + ry, 63), sx = min(x0b + rx, 63);
        patch[t] = pbase[c * 4096 + (sy << 6) + sx];
    }
    __syncthreads();

    // ---- stage 1: halo softmax -> fp16 planes ----
    for (int i = tid; i < HP; i += 256) {
        const int hy = i / HS, hx = i - hy * HS;
        const int y = by * TS + hy - 1;
        const int x = bx * TS + hx - 1;
        _Float16 a16s[NPAIR * 2], d16s[NPAIR * 2], t16s[NPAIR * 2];
        if (((unsigned)y >= (unsigned)HH) | ((unsigned)x >= (unsigned)WW)) {
            TG[i] = 255;
            const _Float16 aP = (_Float16)1e-4f, dP = (_Float16)LOGEPS;
            const _Float16 tP = (_Float16)fmaf((float)aP, (float)dP, 0.0f);
#pragma unroll
            for (int c = 0; c < NC; ++c) { a16s[c] = aP; d16s[c] = dP; t16s[c] = tP; }
        } else {
            TG[i] = tg[(y << 9) + x];
            const float fy = (float)(y * 63) / 511.0f;
            const float fx = (float)(x * 63) / 511.0f;
            const int y0 = (int)fy, x0 = (int)fx;
            const float wy = fy - (float)y0, wx = fx - (float)x0;
            const int y1 = min(y0 + 1, 63), x1 = min(x0 + 1, 63);
            const float omwy = 1.0f - wy, omwx = 1.0f - wx;
            const int o00 = (y0 - y0b) * 5 + (x0 - x0b);
            const int o01 = (y0 - y0b) * 5 + (x1 - x0b);
            const int o10 = (y1 - y0b) * 5 + (x0 - x0b);
            const int o11 = (y1 - y0b) * 5 + (x1 - x0b);

            float v[NC], w[NC];
            float m = -1e30f;
#pragma unroll
            for (int c = 0; c < NC; ++c) {
                const float* pc_ = &patch[c * PS];
                const float a = pc_[o00] * omwy + pc_[o10] * wy;
                const float b = pc_[o01] * omwy + pc_[o11] * wy;
                const float vv = a * omwx + b * wx;
                v[c] = vv;
                m = fmaxf(m, vv);
            }
            float s = 0.0f;
#pragma unroll
            for (int c = 0; c < NC; ++c) { w[c] = __expf(v[c] - m); s += w[c]; }
            const float inv = 1.0f / s;
            const float lns = __logf(s) + m;          // v - lns = ln p
#pragma unroll
            for (int c = 0; c < NC; ++c) {
                const float p = w[c] * inv;
                const float la = fmaxf(v[c] - lns, LOGEPS);     // ln(clip p)
                const float aa = fmaxf(p, 1e-4f);
                const float lb = __logf(fmaxf(1.0f - p, 1e-4f));
                const _Float16 a16 = (_Float16)aa;
                const _Float16 d16 = (_Float16)(la - lb);
                const _Float16 l16 = (_Float16)lb;
                a16s[c] = a16; d16s[c] = d16;
                t16s[c] = (_Float16)fmaf((float)a16, (float)d16, (float)l16);
            }
        }
        a16s[19] = (_Float16)0.0f; d16s[19] = (_Float16)0.0f; t16s[19] = (_Float16)0.0f;
#pragma unroll
        for (int j = 0; j < NPAIR; ++j) {
            f16x2 a2 = {a16s[2 * j], a16s[2 * j + 1]};
            f16x2 t2 = {t16s[2 * j], t16s[2 * j + 1]};
            f16x2 d2 = {d16s[2 * j], d16s[2 * j + 1]};
            uint2 wv; wv.x = bc_u32(a2); wv.y = bc_u32(t2);
            *reinterpret_cast<uint2*>(&AT[i * ATRS + 2 * j]) = wv;   // ds_write_b64
            DP[i * DRS + j] = bc_u32(d2);
        }
    }
    __syncthreads();

    // ---- stage 2 ----
    const int ty = tid >> 4, tx = tid & 15;
    const int hi = (ty + 1) * HS + (tx + 1);
    const int lab = TG[hi];
    const bool interior_blk = (bx > 0) & (bx < 31) & (by > 0) & (by < 31);

    float e_s = 0.0f, ne_s = 0.0f;
    int e_c = 0, ne_c = 0;
    const int DOFF[8] = {-HS - 1, -HS, -HS + 1, -1, 1, HS - 1, HS, HS + 1};
    const f16x2 one2 = {(_Float16)1.0f, (_Float16)1.0f};
    const f16x2 k32 = {(_Float16)3.0f, (_Float16)3.0f};
    const f16x2 z2 = {(_Float16)0.0f, (_Float16)0.0f};

    // prologue (both paths): center d-pairs and derived l-pairs in registers
    f16x2 Dh[NPAIR], Lh[NPAIR];
#pragma unroll
    for (int j = 0; j < NPAIR; ++j) {
        const uint2 rd = *reinterpret_cast<const uint2*>(&AT[hi * ATRS + 2 * j]);
        const f16x2 a2 = bc_h2(rd.x), t2 = bc_h2(rd.y);
        Dh[j] = bc_h2(DP[hi * DRS + j]);
        Lh[j] = t2 - a2 * Dh[j];          // l = t - a*d (pk ops)
    }
    const int plab = lab >> 1, hlab = lab & 1;

    if (interior_blk) {
#pragma unroll
        for (int k = 0; k < 8; ++k) {
            const int np = hi + DOFF[k];
            const int nlab = TG[np];
            const int pn = nlab >> 1, hn = nlab & 1;
            const int wb = np * ATRS;
            float dot = 0.0f;
            f16x2 klLw = z2, klNw = z2;
#pragma unroll
            for (int j = 0; j < NPAIR; ++j) {
                const uint2 rd = *reinterpret_cast<const uint2*>(&AT[wb + 2 * j]);
                const f16x2 a2 = bc_h2(rd.x), t2 = bc_h2(rd.y);
                const f16x2 x2 = a2 * Dh[j] + Lh[j];   // pk_fma
                const f16x2 kl2 = t2 - x2;
                dot = FDOT2(kl2, one2, dot);            // sum_c kl (fp32 acc)
                klLw = (j == plab) ? kl2 : klLw;
                klNw = (j == pn) ? kl2 : klNw;
            }
            const float klL = extf(klLw, hlab);
            const float klN = extf(klNw, hn);
            const bool df = (lab != nlab);
            const float w = df ? 1.0f : 0.0f;
            e_s = fmaf(w, fmaxf(3.0f - klL, 0.0f) + fmaxf(3.0f - klN, 0.0f), e_s);
            ne_s += dot - w * (klL + klN);
            e_c += df ? 2 : 0;
        }
        ne_c = 8 * NC - e_c;
        e_s *= swe[lab];
        ne_s *= swn[lab];
    } else if (lab <= NC - 1) {
        // ---- border path: handles OOB-pad neighbors and reverse-ignore ----
#pragma unroll
        for (int k = 0; k < 8; ++k) {
            const int off = DOFF[k];
            const int rlab = TG[hi - off];
            const int np = hi + off;
            const int nlab = TG[np];
            const int pn = nlab >> 1, hn = nlab & 1;   // pad: pn=127, never selected
            const int wb = np * ATRS;
            float dot = 0.0f, ekall = 0.0f;
            f16x2 klLw = z2, klNw = z2;
#pragma unroll
            for (int j = 0; j < NPAIR; ++j) {
                const uint2 rd = *reinterpret_cast<const uint2*>(&AT[wb + 2 * j]);
                const f16x2 a2 = bc_h2(rd.x), t2 = bc_h2(rd.y);
                const f16x2 x2 = a2 * Dh[j] + Lh[j];
                const f16x2 kl2 = t2 - x2;
                dot = FDOT2(kl2, one2, dot);
                f16x2 m2 = k32 - kl2;
                m2[0] = m2[0] > (_Float16)0.0f ? m2[0] : (_Float16)0.0f;
                m2[1] = m2[1] > (_Float16)0.0f ? m2[1] : (_Float16)0.0f;
                ekall = FDOT2(m2, one2, ekall);         // sum_c relu(3-kl)
                klLw = (j == plab) ? kl2 : klLw;
                klNw = (j == pn) ? kl2 : klNw;
            }
            const float klL = extf(klLw, hlab);
            const float klN = extf(klNw, hn);
            const bool isPad = (nlab == 255);
            const bool df = (lab != nlab) && !isPad;
            const float w = df ? 1.0f : 0.0f;
            const float ek_int = w * (fmaxf(3.0f - klL, 0.0f) + fmaxf(3.0f - klN, 0.0f));
            const float nk_int = dot - w * (klL + klN);
            const float ek_pad = ekall - 3.0f;          // drop pad-class slot (kl=0 -> 3)
            const float ek_k = isPad ? ek_pad : ek_int;
            const float nk_k = isPad ? 0.0f : nk_int;
            const int pc = isPad ? NC : (df ? 2 : 0);
            const bool valid = (rlab <= NC - 1);
            const float vf = valid ? 1.0f : 0.0f;
            e_s = fmaf(vf, ek_k, e_s);
            ne_s = fmaf(vf, nk_k, ne_s);
            e_c += valid ? pc : 0;
            ne_c += valid ? (NC - pc) : 0;
        }
        e_s *= swe[lab];
        ne_s *= swn[lab];
    }

    // ---- block reduction ----
#pragma unroll
    for (int off = 32; off > 0; off >>= 1) {
        e_s  += __shfl_down(e_s, off, 64);
        ne_s += __shfl_down(ne_s, off, 64);
        e_c  += __shfl_down(e_c, off, 64);
        ne_c += __shfl_down(ne_c, off, 64);
    }
    __shared__ float r_es[4], r_ns[4];
    __shared__ int r_ec[4], r_nc[4];
    const int wid = tid >> 6, lane = tid & 63;
    if (lane == 0) { r_es[wid] = e_s; r_ns[wid] = ne_s; r_ec[wid] = e_c; r_nc[wid] = ne_c; }
    __syncthreads();
    if (tid == 0) {
        float tes = 0.0f, tns = 0.0f;
        int tec = 0, tnc = 0;
#pragma unroll
        for (int w = 0; w < 4; ++w) { tes += r_es[w]; tns += r_ns[w]; tec += r_ec[w]; tnc += r_nc[w]; }
        const int bid = (blockIdx.z * gridDim.y + blockIdx.y) * gridDim.x + blockIdx.x;
        pb[bid].es = tes; pb[bid].ns = tns; pb[bid].ec = tec; pb[bid].nc = tnc;
    }
}

// ---------------- final reduce (1 block) ----------------
__global__ __launch_bounds__(256) void k_final(const Part* __restrict__ pb,
                                               float* __restrict__ out) {
    const int tid = threadIdx.x;
    double es = 0.0, ns = 0.0;
    long long ec = 0, nc = 0;
    for (int i = tid; i < NBLK; i += 256) {
        es += (double)pb[i].es; ns += (double)pb[i].ns;
        ec += pb[i].ec; nc += pb[i].nc;
    }
#pragma unroll
    for (int off = 32; off > 0; off >>= 1) {
        es += __shfl_down(es, off, 64);
        ns += __shfl_down(ns, off, 64);
        ec += __shfl_down(ec, off, 64);
        nc += __shfl_down(nc, off, 64);
    }
    __shared__ double ses[4], sns[4];
    __shared__ long long sec[4], snc[4];
    const int wid = tid >> 6, lane = tid & 63;
    if (lane == 0) { ses[wid] = es; sns[wid] = ns; sec[wid] = ec; snc[wid] = nc; }
    __syncthreads();
    if (tid == 0) {
        double tes = 0.0, tns = 0.0;
        long long tec = 0, tnc = 0;
#pragma unroll
        for (int w = 0; w < 4; ++w) { tes += ses[w]; tns += sns[w]; tec += sec[w]; tnc += snc[w]; }
        double ecd = (double)tec; if (ecd < 1.0) ecd = 1.0;
        double ncd = (double)tnc; if (ncd < 1.0) ncd = 1.0;
        out[0] = (float)((tes / ecd) * 0.01 + (tns / ncd) * 0.01);
    }
}

extern "C" void kernel_launch(void* const* d_in, const int* in_sizes, int n_in,
                              void* d_out, int out_size, void* d_ws, size_t ws_size,
                              hipStream_t stream) {
    const float* preds      = (const float*)d_in[0];  // (2,19,64,64) fp32
    const int*   targets    = (const int*)d_in[1];    // (2,512,512) int32
    const float* w_edge     = (const float*)d_in[2];  // (1,1,1,19,1,3) fp32
    const float* w_not_edge = (const float*)d_in[3];

    Part* pb = (Part*)d_ws;

    dim3 grid(WW / TS, HH / TS, NB);
    k_fused<<<grid, 256, 0, stream>>>(preds, targets, w_edge, w_not_edge, pb);
    k_final<<<1, 256, 0, stream>>>(pb, (float*)d_out);
}

// Round 10
// 99.502 us; speedup vs baseline: 1.1611x; 1.0456x over previous
//
#include <hip/hip_runtime.h>
#include <stdint.h>

// AAF loss, round 10: register-resident center tables + 5 blocks/CU.
// Each thread computes its OWN interior pixel's softmax -> keeps (d, l) pairs and
// label in REGISTERS (they are never read by other pixels); only (a, t) go to LDS
// (needed by neighbors). Threads 0..67 additionally compute the 68-pixel halo ring.
// LDS ~31.9 KB (AT 28.5K + TG 1.3K + patch 1.9K + weights) -> 5 blocks/CU.
// Stage 2 identical to R9's fully-static packed-fp16 loop:
//   kl2 = t2_n - (a2_n * d2_h + l2_h); sum via fdot2; kl@lab / kl@nlab captured
//   in-loop via cndmask. Zero dynamic LDS reads, zero logf in stage 2.

#define NC 19
#define HH 512
#define WW 512
#define NB 2
#define TS 16
#define HS 18                          // TS + 2 halo
#define HP (HS * HS)                   // 324
#define NPAIR 10
#define ATRS 22                        // (a2,t2) interleaved row stride in words
#define PS 25                          // 5x5 source patch per class
#define NBLK (NB * (HH / TS) * (WW / TS))   // 2048
#define LOGEPS -9.210340371976182f     // log(1e-4)

typedef _Float16 f16x2 __attribute__((ext_vector_type(2)));

#if __has_builtin(__builtin_amdgcn_fdot2)
#define FDOT2(a, b, c) __builtin_amdgcn_fdot2((a), (b), (c), false)
#else
#define FDOT2(a, b, c) fmaf((float)(a)[1], (float)(b)[1], fmaf((float)(a)[0], (float)(b)[0], (c)))
#endif

struct Part { float es, ns; int ec, nc; };

union U32F2 { uint32_t u; f16x2 h; };
__device__ __forceinline__ uint32_t bc_u32(f16x2 v) { U32F2 x; x.h = v; return x.u; }
__device__ __forceinline__ f16x2 bc_h2(uint32_t v) { U32F2 x; x.u = v; return x.h; }
__device__ __forceinline__ float extf(f16x2 v, int h) { return h ? (float)v[1] : (float)v[0]; }

// Compute one pixel's softmax -> write packed (a2,t2) row; optionally keep (d2,l2)
// in registers. Returns the label (255 for image-OOB pad pixels).
template <bool KEEP>
__device__ __forceinline__ int pix_compute(const float* __restrict__ patch,
                                           const int* __restrict__ tg,
                                           int y, int x, int y0b, int x0b,
                                           uint32_t* __restrict__ ATrow,
                                           f16x2* Dh, f16x2* Lh) {
    _Float16 a16s[NPAIR * 2], t16s[NPAIR * 2], d16s[NPAIR * 2], l16s[NPAIR * 2];
    int lab;
    if (((unsigned)y >= (unsigned)HH) | ((unsigned)x >= (unsigned)WW)) {
        lab = 255;
        const _Float16 aP = (_Float16)1e-4f, dP = (_Float16)LOGEPS;
        const _Float16 tP = (_Float16)((float)aP * (float)dP);
#pragma unroll
        for (int c = 0; c < NC; ++c) {
            a16s[c] = aP; d16s[c] = dP; l16s[c] = (_Float16)0.0f; t16s[c] = tP;
        }
    } else {
        lab = tg[(y << 9) + x];
        const float fy = (float)(y * 63) / 511.0f;
        const float fx = (float)(x * 63) / 511.0f;
        const int y0 = (int)fy, x0 = (int)fx;
        const float wy = fy - (float)y0, wx = fx - (float)x0;
        const int y1 = min(y0 + 1, 63), x1 = min(x0 + 1, 63);
        const float omwy = 1.0f - wy, omwx = 1.0f - wx;
        const int o00 = (y0 - y0b) * 5 + (x0 - x0b);
        const int o01 = (y0 - y0b) * 5 + (x1 - x0b);
        const int o10 = (y1 - y0b) * 5 + (x0 - x0b);
        const int o11 = (y1 - y0b) * 5 + (x1 - x0b);

        float v[NC], w[NC];
        float m = -1e30f;
#pragma unroll
        for (int c = 0; c < NC; ++c) {
            const float* pc_ = &patch[c * PS];
            const float a = pc_[o00] * omwy + pc_[o10] * wy;
            const float b = pc_[o01] * omwy + pc_[o11] * wy;
            const float vv = a * omwx + b * wx;
            v[c] = vv;
            m = fmaxf(m, vv);
        }
        float s = 0.0f;
#pragma unroll
        for (int c = 0; c < NC; ++c) { w[c] = __expf(v[c] - m); s += w[c]; }
        const float inv = 1.0f / s;
        const float lns = __logf(s) + m;          // v - lns = ln p
#pragma unroll
        for (int c = 0; c < NC; ++c) {
            const float p = w[c] * inv;
            const float la = fmaxf(v[c] - lns, LOGEPS);     // ln(clip p)
            const float aa = fmaxf(p, 1e-4f);
            const float lb = __logf(fmaxf(1.0f - p, 1e-4f));
            const _Float16 a16 = (_Float16)aa;
            const _Float16 d16 = (_Float16)(la - lb);
            const _Float16 l16 = (_Float16)lb;
            a16s[c] = a16; d16s[c] = d16; l16s[c] = l16;
            t16s[c] = (_Float16)fmaf((float)a16, (float)d16, (float)l16);
        }
    }
    a16s[19] = (_Float16)0.0f; t16s[19] = (_Float16)0.0f;
    d16s[19] = (_Float16)0.0f; l16s[19] = (_Float16)0.0f;
#pragma unroll
    for (int j = 0; j < NPAIR; ++j) {
        uint2 wv;
        wv.x = bc_u32((f16x2){a16s[2 * j], a16s[2 * j + 1]});
        wv.y = bc_u32((f16x2){t16s[2 * j], t16s[2 * j + 1]});
        *reinterpret_cast<uint2*>(ATrow + 2 * j) = wv;      // ds_write_b64
        if (KEEP) {
            Dh[j] = (f16x2){d16s[2 * j], d16s[2 * j + 1]};
            Lh[j] = (f16x2){l16s[2 * j], l16s[2 * j + 1]};
        }
    }
    return lab;
}

__global__ __launch_bounds__(256, 5) void k_fused(const float* __restrict__ preds,
                                                  const int* __restrict__ targets,
                                                  const float* __restrict__ w_edge,
                                                  const float* __restrict__ w_not_edge,
                                                  Part* __restrict__ pb) {
    __shared__ __align__(16) uint32_t AT[HP * ATRS];  // (a2,t2) interleaved pairs
    __shared__ int   TG[HP];
    __shared__ float swe[NC], swn[NC];
    __shared__ float patch[NC * PS];
    __shared__ float r_es[4], r_ns[4];
    __shared__ int r_ec[4], r_nc[4];

    const int tid = threadIdx.x;
    const int bx = blockIdx.x, by = blockIdx.y, n = blockIdx.z;

    if (tid < NC) {
        {
            float a = w_edge[tid * 3 + 0], b = w_edge[tid * 3 + 1], c = w_edge[tid * 3 + 2];
            float m = fmaxf(a, fmaxf(b, c));
            float ea = __expf(a - m), eb = __expf(b - m), ec = __expf(c - m);
            swe[tid] = ea / (ea + eb + ec);
        }
        {
            float a = w_not_edge[tid * 3 + 0], b = w_not_edge[tid * 3 + 1], c = w_not_edge[tid * 3 + 2];
            float m = fmaxf(a, fmaxf(b, c));
            float ea = __expf(a - m), eb = __expf(b - m), ec = __expf(c - m);
            swn[tid] = ea / (ea + eb + ec);
        }
    }

    const int* tg = targets + (n << 18);
    const float* pbase = preds + (size_t)n * NC * 4096;

    // ---- stage 0: stage 5x5x19 source patch ----
    const int yT = max(by * TS - 1, 0), xL = max(bx * TS - 1, 0);
    const int y0b = (yT * 63) / 511, x0b = (xL * 63) / 511;
    for (int t = tid; t < NC * PS; t += 256) {
        const int c = t / PS, r = t - c * PS;
        const int ry = r / 5, rx = r - ry * 5;
        const int sy = min(y0b + ry, 63), sx = min(x0b + rx, 63);
        patch[t] = pbase[c * 4096 + (sy << 6) + sx];
    }
    __syncthreads();

    // ---- stage 1: own interior pixel (keep d,l,lab in regs) + halo ring ----
    const int ty = tid >> 4, tx = tid & 15;
    const int hi = (ty + 1) * HS + (tx + 1);
    f16x2 Dh[NPAIR], Lh[NPAIR];
    const int lab = pix_compute<true>(patch, tg, by * TS + ty, bx * TS + tx,
                                      y0b, x0b, &AT[hi * ATRS], Dh, Lh);
    TG[hi] = lab;

    if (tid < 68) {
        int i;
        if (tid < 18)      i = tid;                       // top row
        else if (tid < 36) i = 306 + (tid - 18);          // bottom row
        else if (tid < 52) i = (tid - 35) * HS;           // left col (rows 1..16)
        else               i = (tid - 51) * HS + 17;      // right col (rows 1..16)
        const int hy = i / HS, hx = i - hy * HS;
        const int lab2 = pix_compute<false>(patch, tg, by * TS + hy - 1, bx * TS + hx - 1,
                                            y0b, x0b, &AT[i * ATRS], nullptr, nullptr);
        TG[i] = lab2;
    }
    __syncthreads();

    // ---- stage 2 ----
    const bool interior_blk = (bx > 0) & (bx < 31) & (by > 0) & (by < 31);

    float e_s = 0.0f, ne_s = 0.0f;
    int e_c = 0, ne_c = 0;
    const int DOFF[8] = {-HS - 1, -HS, -HS + 1, -1, 1, HS - 1, HS, HS + 1};
    const f16x2 one2 = {(_Float16)1.0f, (_Float16)1.0f};
    const f16x2 k32 = {(_Float16)3.0f, (_Float16)3.0f};
    const f16x2 z2 = {(_Float16)0.0f, (_Float16)0.0f};
    const int plab = lab >> 1, hlab = lab & 1;

    if (interior_blk) {
#pragma unroll
        for (int k = 0; k < 8; ++k) {
            const int np = hi + DOFF[k];
            const int nlab = TG[np];
            const int pn = nlab >> 1, hn = nlab & 1;
            const int wb = np * ATRS;
            float dot = 0.0f;
            f16x2 klLw = z2, klNw = z2;
#pragma unroll
            for (int j = 0; j < NPAIR; ++j) {
                const uint2 rd = *reinterpret_cast<const uint2*>(&AT[wb + 2 * j]);
                const f16x2 a2 = bc_h2(rd.x), t2 = bc_h2(rd.y);
                const f16x2 x2 = a2 * Dh[j] + Lh[j];   // pk_fma
                const f16x2 kl2 = t2 - x2;
                dot = FDOT2(kl2, one2, dot);            // sum_c kl (fp32 acc)
                klLw = (j == plab) ? kl2 : klLw;
                klNw = (j == pn) ? kl2 : klNw;
            }
            const float klL = extf(klLw, hlab);
            const float klN = extf(klNw, hn);
            const bool df = (lab != nlab);
            const float w = df ? 1.0f : 0.0f;
            e_s = fmaf(w, fmaxf(3.0f - klL, 0.0f) + fmaxf(3.0f - klN, 0.0f), e_s);
            ne_s += dot - w * (klL + klN);
            e_c += df ? 2 : 0;
        }
        ne_c = 8 * NC - e_c;
        e_s *= swe[lab];
        ne_s *= swn[lab];
    } else if (lab <= NC - 1) {
        // ---- border path: handles OOB-pad neighbors and reverse-ignore ----
#pragma unroll
        for (int k = 0; k < 8; ++k) {
            const int off = DOFF[k];
            const int rlab = TG[hi - off];
            const int np = hi + off;
            const int nlab = TG[np];
            const int pn = nlab >> 1, hn = nlab & 1;   // pad: pn=127, never selected
            const int wb = np * ATRS;
            float dot = 0.0f, ekall = 0.0f;
            f16x2 klLw = z2, klNw = z2;
#pragma unroll
            for (int j = 0; j < NPAIR; ++j) {
                const uint2 rd = *reinterpret_cast<const uint2*>(&AT[wb + 2 * j]);
                const f16x2 a2 = bc_h2(rd.x), t2 = bc_h2(rd.y);
                const f16x2 x2 = a2 * Dh[j] + Lh[j];
                const f16x2 kl2 = t2 - x2;
                dot = FDOT2(kl2, one2, dot);
                f16x2 m2 = k32 - kl2;
                m2[0] = m2[0] > (_Float16)0.0f ? m2[0] : (_Float16)0.0f;
                m2[1] = m2[1] > (_Float16)0.0f ? m2[1] : (_Float16)0.0f;
                ekall = FDOT2(m2, one2, ekall);         // sum_c relu(3-kl)
                klLw = (j == plab) ? kl2 : klLw;
                klNw = (j == pn) ? kl2 : klNw;
            }
            const float klL = extf(klLw, hlab);
            const float klN = extf(klNw, hn);
            const bool isPad = (nlab == 255);
            const bool df = (lab != nlab) && !isPad;
            const float w = df ? 1.0f : 0.0f;
            const float ek_int = w * (fmaxf(3.0f - klL, 0.0f) + fmaxf(3.0f - klN, 0.0f));
            const float nk_int = dot - w * (klL + klN);
            const float ek_pad = ekall - 3.0f;          // drop pad-class slot (kl=0 -> 3)
            const float ek_k = isPad ? ek_pad : ek_int;
            const float nk_k = isPad ? 0.0f : nk_int;
            const int pc = isPad ? NC : (df ? 2 : 0);
            const bool valid = (rlab <= NC - 1);
            const float vf = valid ? 1.0f : 0.0f;
            e_s = fmaf(vf, ek_k, e_s);
            ne_s = fmaf(vf, nk_k, ne_s);
            e_c += valid ? pc : 0;
            ne_c += valid ? (NC - pc) : 0;
        }
        e_s *= swe[lab];
        ne_s *= swn[lab];
    }

    // ---- block reduction ----
#pragma unroll
    for (int off = 32; off > 0; off >>= 1) {
        e_s  += __shfl_down(e_s, off, 64);
        ne_s += __shfl_down(ne_s, off, 64);
        e_c  += __shfl_down(e_c, off, 64);
        ne_c += __shfl_down(ne_c, off, 64);
    }
    const int wid = tid >> 6, lane = tid & 63;
    if (lane == 0) { r_es[wid] = e_s; r_ns[wid] = ne_s; r_ec[wid] = e_c; r_nc[wid] = ne_c; }
    __syncthreads();
    if (tid == 0) {
        float tes = 0.0f, tns = 0.0f;
        int tec = 0, tnc = 0;
#pragma unroll
        for (int w = 0; w < 4; ++w) { tes += r_es[w]; tns += r_ns[w]; tec += r_ec[w]; tnc += r_nc[w]; }
        const int bid = (blockIdx.z * gridDim.y + blockIdx.y) * gridDim.x + blockIdx.x;
        pb[bid].es = tes; pb[bid].ns = tns; pb[bid].ec = tec; pb[bid].nc = tnc;
    }
}

// ---------------- final reduce (1 block) ----------------
__global__ __launch_bounds__(256) void k_final(const Part* __restrict__ pb,
                                               float* __restrict__ out) {
    const int tid = threadIdx.x;
    double es = 0.0, ns = 0.0;
    long long ec = 0, nc = 0;
    for (int i = tid; i < NBLK; i += 256) {
        es += (double)pb[i].es; ns += (double)pb[i].ns;
        ec += pb[i].ec; nc += pb[i].nc;
    }
#pragma unroll
    for (int off = 32; off > 0; off >>= 1) {
        es += __shfl_down(es, off, 64);
        ns += __shfl_down(ns, off, 64);
        ec += __shfl_down(ec, off, 64);
        nc += __shfl_down(nc, off, 64);
    }
    __shared__ double ses[4], sns[4];
    __shared__ long long sec[4], snc[4];
    const int wid = tid >> 6, lane = tid & 63;
    if (lane == 0) { ses[wid] = es; sns[wid] = ns; sec[wid] = ec; snc[wid] = nc; }
    __syncthreads();
    if (tid == 0) {
        double tes = 0.0, tns = 0.0;
        long long tec = 0, tnc = 0;
#pragma unroll
        for (int w = 0; w < 4; ++w) { tes += ses[w]; tns += sns[w]; tec += sec[w]; tnc += snc[w]; }
        double ecd = (double)tec; if (ecd < 1.0) ecd = 1.0;
        double ncd = (double)tnc; if (ncd < 1.0) ncd = 1.0;
        out[0] = (float)((tes / ecd) * 0.01 + (tns / ncd) * 0.01);
    }
}

extern "C" void kernel_launch(void* const* d_in, const int* in_sizes, int n_in,
                              void* d_out, int out_size, void* d_ws, size_t ws_size,
                              hipStream_t stream) {
    const float* preds      = (const float*)d_in[0];  // (2,19,64,64) fp32
    const int*   targets    = (const int*)d_in[1];    // (2,512,512) int32
    const float* w_edge     = (const float*)d_in[2];  // (1,1,1,19,1,3) fp32
    const float* w_not_edge = (const float*)d_in[3];

    Part* pb = (Part*)d_ws;

    dim3 grid(WW / TS, HH / TS, NB);
    k_fused<<<grid, 256, 0, stream>>>(preds, targets, w_edge, w_not_edge, pb);
    k_final<<<1, 256, 0, stream>>>(pb, (float*)d_out);
}